// Round 10
// baseline (190.627 us; speedup 1.0000x reference)
//
#include <hip/hip_runtime.h>
#include <stdint.h>

typedef unsigned short ushort_t;
typedef __attribute__((ext_vector_type(8))) short bf16x8;   // 4 VGPRs, 8 bf16
typedef __attribute__((ext_vector_type(4))) float f32x4;    // MFMA C/D

#define B_   128
#define S_   50
#define D_   128
#define ALPHA_ 0.2f

__device__ __forceinline__ float bf2f(ushort_t u){
  return __uint_as_float(((uint32_t)u) << 16);
}
__device__ __forceinline__ ushort_t f2bf(float f){
  uint32_t x = __float_as_uint(f);
  x = (x + 0x7fffu + ((x >> 16) & 1u)) >> 16;
  return (ushort_t)x;
}
__device__ __forceinline__ float leaky(float x){ return x >= 0.f ? x : ALPHA_*x; }

// per-block dtype detect: bf16-packed (1) vs f32 (0), from emb's first 64 words
__device__ __forceinline__ int detect_flag_block(const uint32_t* __restrict__ emb_raw){
  __shared__ int flg;
  if (threadIdx.x == 0){
    int ok = 1;
    for (int i = 0; i < 64; i++){
      uint32_t lo = emb_raw[i] & 0xffffu;
      uint32_t ex = (lo >> 7) & 0xFFu;
      if (!(lo == 0u || (ex >= 64u && ex <= 126u))) ok = 0;
    }
    flg = ok;
  }
  __syncthreads();
  return flg;
}

// ===========================================================================
// K1: cvt_all + prep_frags + sess + local, one launch (round-5 proven, 185.1).
// blocks: [0,512) local | [512,576) sess | [576,3750) cvt (16B/thr) |
//         [3750,3798) prep
// When flag==1 && skip_emb: cvt skips the emb segment (k2 reads p0 directly).
// ===========================================================================
#define NLOCAL_ 512
#define NSESS_  64
#define NCVT_   3174
#define NPREP_  48
#define CVT_BASE_   (NLOCAL_ + NSESS_)
#define PREP_BASE_  (CVT_BASE_ + NCVT_)
#define K1_GRID_    (PREP_BASE_ + NPREP_)

__global__ __launch_bounds__(256) void k1(
    const int* __restrict__ inputs, const int* __restrict__ adj,
    const int* __restrict__ item, const int* __restrict__ mask,
    const void* __restrict__ p0, const void* __restrict__ p1,
    const void* __restrict__ p2, const void* __restrict__ p3,
    const void* __restrict__ p4, const void* __restrict__ p5,
    ushort_t* __restrict__ emb_b, uint4* __restrict__ w1f, uint4* __restrict__ w3f,
    ushort_t* __restrict__ sessb, ushort_t* __restrict__ hlb, int skip_emb)
{
  int blk = blockIdx.x, tid = threadIdx.x;
  int flag = detect_flag_block((const uint32_t*)p0);

  if (blk < NLOCAL_){
    __shared__ ushort_t hS[64][136];
    __shared__ float    attS[16][68];
    __shared__ int      sids[64];
    __shared__ ushort_t alS[512];
    int b  = blk >> 2;
    int mi = blk & 3;
    if (tid < 64) sids[tid] = (tid < S_) ? inputs[b*S_ + tid] : 0;
    for (int i = tid; i < 512; i += 256)
      alS[i] = flag ? ((const ushort_t*)p1)[i] : f2bf(((const float*)p1)[i]);
    __syncthreads();
    if (flag){
      const ushort_t* e16 = (const ushort_t*)p0;
      for (int idx = tid; idx < 64*16; idx += 256){
        int j = idx >> 4, ch = idx & 15;
        uint4 v = {0u, 0u, 0u, 0u};
        if (j < S_) v = *(const uint4*)(e16 + (size_t)sids[j]*D_ + ch*8);
        *(uint4*)(&hS[j][ch*8]) = v;
      }
    } else {
      const float* ef = (const float*)p0;
      for (int idx = tid; idx < 64*32; idx += 256){
        int j = idx >> 5, ch = idx & 31;
        union { ushort_t u[4]; uint2 d2; } o;
        o.d2 = make_uint2(0u, 0u);
        if (j < S_){
          float4 v = *(const float4*)(ef + (size_t)sids[j]*D_ + ch*4);
          o.u[0]=f2bf(v.x); o.u[1]=f2bf(v.y); o.u[2]=f2bf(v.z); o.u[3]=f2bf(v.w);
        }
        *(uint2*)(&hS[j][ch*4]) = o.d2;
      }
    }
    for (int idx = tid; idx < 16*64; idx += 256)
      attS[idx >> 6][idx & 63] = -9.0e15f;
    __syncthreads();

    int lane = tid & 63, wv = tid >> 6;
    int q = lane >> 4, c = lane & 15;

    f32x4 Eacc[4];
    #pragma unroll
    for (int ni = 0; ni < 4; ni++) Eacc[ni] = (f32x4){0.f,0.f,0.f,0.f};
    #pragma unroll
    for (int kt = 0; kt < 4; kt++){
      uint4 av = *(const uint4*)(alS + wv*D_ + kt*32 + q*8);
      const uint32_t* ap = (const uint32_t*)&av;
      uint4 hv = *(const uint4*)(&hS[mi*16 + c][kt*32 + q*8]);
      const uint32_t* hp = (const uint32_t*)&hv;
      union { ushort_t u[8]; bf16x8 v; } afr;
      #pragma unroll
      for (int p = 0; p < 4; p++){
        float x0 = __uint_as_float(hp[p] << 16)         * __uint_as_float(ap[p] << 16);
        float x1 = __uint_as_float(hp[p] & 0xffff0000u) * __uint_as_float(ap[p] & 0xffff0000u);
        afr.u[2*p]   = f2bf(x0);
        afr.u[2*p+1] = f2bf(x1);
      }
      #pragma unroll
      for (int ni = 0; ni < 4; ni++){
        union { uint4 q4; bf16x8 v; } bfr;
        bfr.q4 = *(const uint4*)(&hS[ni*16 + c][kt*32 + q*8]);
        Eacc[ni] = __builtin_amdgcn_mfma_f32_16x16x32_bf16(afr.v, bfr.v, Eacc[ni], 0,0,0);
      }
    }
    const int* adjb = adj + (size_t)b*S_*S_;
    #pragma unroll
    for (int ni = 0; ni < 4; ni++){
      int j = ni*16 + c;
      #pragma unroll
      for (int r = 0; r < 4; r++){
        int i = mi*16 + q*4 + r;
        if (i < S_ && j < S_){
          int kk = adjb[i*S_ + j];
          if (kk == wv + 1) attS[q*4 + r][j] = leaky(Eacc[ni][r]);
        }
      }
    }
    __syncthreads();
    {
      int r  = tid >> 4;
      int cg = tid & 15;
      int i  = mi*16 + r;
      float v0 = attS[r][cg*4+0], v1 = attS[r][cg*4+1];
      float v2 = attS[r][cg*4+2], v3 = attS[r][cg*4+3];
      float mx = fmaxf(fmaxf(v0,v1), fmaxf(v2,v3));
      #pragma unroll
      for (int off = 1; off < 16; off <<= 1) mx = fmaxf(mx, __shfl_xor(mx, off, 16));
      float e0 = (cg*4+0 < S_) ? __expf(v0 - mx) : 0.f;
      float e1 = (cg*4+1 < S_) ? __expf(v1 - mx) : 0.f;
      float e2 = (cg*4+2 < S_) ? __expf(v2 - mx) : 0.f;
      float e3 = (cg*4+3 < S_) ? __expf(v3 - mx) : 0.f;
      float s = e0 + e1 + e2 + e3;
      #pragma unroll
      for (int off = 1; off < 16; off <<= 1) s += __shfl_xor(s, off, 16);
      float inv = (i < S_) ? 1.f / s : 0.f;
      attS[r][cg*4+0] = e0*inv;
      attS[r][cg*4+1] = e1*inv;
      attS[r][cg*4+2] = e2*inv;
      attS[r][cg*4+3] = e3*inv;
    }
    __syncthreads();
    f32x4 Pacc[2];
    Pacc[0] = (f32x4){0.f,0.f,0.f,0.f};
    Pacc[1] = (f32x4){0.f,0.f,0.f,0.f};
    #pragma unroll
    for (int kt = 0; kt < 2; kt++){
      union { ushort_t u[8]; bf16x8 v; } afr;
      const float* arow = &attS[c][kt*32 + q*8];
      #pragma unroll
      for (int j = 0; j < 8; j++) afr.u[j] = f2bf(arow[j]);
      #pragma unroll
      for (int nn = 0; nn < 2; nn++){
        int ni = 2*wv + nn;
        union { ushort_t u[8]; bf16x8 v; } bfr;
        #pragma unroll
        for (int jj = 0; jj < 8; jj++)
          bfr.u[jj] = hS[kt*32 + q*8 + jj][ni*16 + c];
        Pacc[nn] = __builtin_amdgcn_mfma_f32_16x16x32_bf16(afr.v, bfr.v, Pacc[nn], 0,0,0);
      }
    }
    #pragma unroll
    for (int nn = 0; nn < 2; nn++){
      int d = (2*wv + nn)*16 + c;
      #pragma unroll
      for (int r = 0; r < 4; r++){
        int i = mi*16 + q*4 + r;
        if (i < S_) hlb[((size_t)b*S_ + i)*D_ + d] = f2bf(Pacc[nn][r]);
      }
    }
  } else if (blk < CVT_BASE_){
    // ---- sess ----
    int b = (blk - NLOCAL_)*2 + (tid >> 7);
    int d = tid & 127;
    float acc = 0.f, den = 0.f;
    if (flag){
      const ushort_t* e16 = (const ushort_t*)p0;
      for (int s = 0; s < S_; s++){
        float fm = (float)mask[b*S_ + s];
        int id = item[b*S_ + s];
        acc += fm * bf2f(e16[(size_t)id*D_ + d]);
        den += fm;
      }
    } else {
      const float* ef = (const float*)p0;
      for (int s = 0; s < S_; s++){
        float fm = (float)mask[b*S_ + s];
        int id = item[b*S_ + s];
        acc += fm * ef[(size_t)id*D_ + d];
        den += fm;
      }
    }
    sessb[b*D_ + d] = f2bf(acc / den);
  } else if (blk < PREP_BASE_){
    // ---- cvt: six float tensors -> contiguous bf16, 16 B/thread ----
    const int seg_end[6] = {6400000, 6400512, 6433280, 6433536, 6499072, 6499328};
    int base = ((blk - CVT_BASE_)*256 + tid) * 8;
    if (base >= 6499328) return;
    if (flag && skip_emb && base < 6400000) return;   // emb read direct from p0
    int s = 0;
    while (base >= seg_end[s]) s++;
    int segbase = (s == 0) ? 0 : seg_end[s-1];
    const void* src = (s==0)?p0:(s==1)?p1:(s==2)?p2:(s==3)?p3:(s==4)?p4:p5;
    int off = base - segbase;
    union { ushort_t u[8]; uint4 q4; } o;
    if (flag){
      o.q4 = *(const uint4*)((const ushort_t*)src + off);
    } else {
      const float* fp = (const float*)src + off;
      float4 v0 = *(const float4*)(fp);
      float4 v1 = *(const float4*)(fp + 4);
      o.u[0]=f2bf(v0.x); o.u[1]=f2bf(v0.y); o.u[2]=f2bf(v0.z); o.u[3]=f2bf(v0.w);
      o.u[4]=f2bf(v1.x); o.u[5]=f2bf(v1.y); o.u[6]=f2bf(v1.z); o.u[7]=f2bf(v1.w);
    }
    *(uint4*)(emb_b + base) = o.q4;
  } else {
    // ---- prep_frags: w1/w3 -> pre-swizzled MFMA fragment buffers ----
    int id = (blk - PREP_BASE_)*256 + tid;
    if (id >= 12288) return;
    if (id < 4096){
      int h = id >> 11, i = id & 2047;
      int kt = i >> 9, rem = i & 511, t = rem >> 6, ln = rem & 63;
      int q = ln >> 4, c = ln & 15;
      union { ushort_t u[8]; uint4 q4; } e;
      #pragma unroll
      for (int j = 0; j < 8; j++){
        int idx = h*16384 + (32*kt + q*8 + j)*128 + 16*t + c;
        e.u[j] = flag ? ((const ushort_t*)p2)[idx] : f2bf(((const float*)p2)[idx]);
      }
      w1f[h*2048 + i] = e.q4;
    } else {
      int id2 = id - 4096;
      int h = id2 >> 12, i = id2 & 4095;
      int kt = i >> 9, rem = i & 511, t = rem >> 6, ln = rem & 63;
      int q = ln >> 4, c = ln & 15;
      union { ushort_t u[8]; uint4 q4; } e;
      #pragma unroll
      for (int j = 0; j < 8; j++){
        int idx = h*32768 + (32*kt + q*8 + j)*128 + 16*t + c;
        e.u[j] = flag ? ((const ushort_t*)p4)[idx] : f2bf(((const float*)p4)[idx]);
      }
      w3f[h*4096 + i] = e.q4;
    }
  }
}

// ===========================================================================
// K2: score2_ab (long blocks FIRST, nid-prefetch, SW-pipelined row gathers)
//     + tprep (4 row-tiles/stage).
// blocks [0,768): score2_ab | [768,1160): tprep (256 rows/block).
// emb operand selected per-block: p0 if bf16-packed, else emb_b.
// ===========================================================================
#define NT2SCORE_ 768
#define NT2TPREP_ 392
#define K2_GRID_  (NT2SCORE_ + NT2TPREP_)

__global__ __launch_bounds__(256) void k2(
    const void* __restrict__ p0, const ushort_t* __restrict__ emb_b,
    const uint4* __restrict__ w3f,
    ushort_t* __restrict__ Tt, ushort_t* __restrict__ Tb,
    const ushort_t* __restrict__ sessb,
    const int* __restrict__ neigh1, const int* __restrict__ adj_all,
    const uint4* __restrict__ w1f, const ushort_t* __restrict__ w2,
    float* __restrict__ score)
{
  __shared__ uint4 frag[2048];
  __shared__ ushort_t sS[128];
  __shared__ int nidS[304];
  int blk = blockIdx.x, tid = threadIdx.x;
  int flag = detect_flag_block((const uint32_t*)p0);
  const ushort_t* emb = flag ? (const ushort_t*)p0 : emb_b;

  if (blk >= NT2SCORE_){
    // ---- tprep: T = emb @ w3hop0; one half per block, 4 x 64 rows ----
    int tp   = blk - NT2SCORE_;
    int half = tp & 1;
    int rowbase0 = (tp >> 1) * 256;
    for (int i = tid; i < 2048; i += 256) frag[i] = w3f[half*2048 + i];
    __syncthreads();
    int lane = tid & 63, wave = tid >> 6;
    int m = lane & 15, q = lane >> 4;
    ushort_t* Tdst = half ? Tb : Tt;
    #pragma unroll
    for (int rit = 0; rit < 4; rit++){
      int row = rowbase0 + rit*64 + wave*16 + m;
      int rowc = row < 50000 ? row : 49999;
      f32x4 acc[8];
      #pragma unroll
      for (int t = 0; t < 8; t++) acc[t] = (f32x4){0.f,0.f,0.f,0.f};
      #pragma unroll
      for (int kt = 0; kt < 4; kt++){
        union { uint4 q4; bf16x8 v; } bfr;
        bfr.q4 = *(const uint4*)(emb + (size_t)rowc*D_ + kt*32 + q*8);
        #pragma unroll
        for (int t = 0; t < 8; t++){
          union { uint4 q4; bf16x8 v; } af;
          af.q4 = frag[(kt*8 + t)*64 + lane];
          acc[t] = __builtin_amdgcn_mfma_f32_16x16x32_bf16(af.v, bfr.v, acc[t], 0, 0, 0);
        }
      }
      if (row < 50000){
        ushort_t* dst = Tdst + (size_t)row*D_;
        #pragma unroll
        for (int t = 0; t < 8; t++){
          int col0 = 16*t + q*4;
          union { ushort_t u[4]; uint2 d2; } pk;
          #pragma unroll
          for (int r = 0; r < 4; r++) pk.u[r] = f2bf(acc[t][r]);
          *(uint2*)(dst + col0) = pk.d2;
        }
      }
    }
    return;
  }

  // ---- score2_ab: sess folded into w1-frag, nids prefetched to LDS,
  //      row gathers software-pipelined one tile ahead ----
  int b2  = blk;
  int sb  = b2 / 6;
  int sub = b2 - sb*6;
  int grp = sub >> 1;
  int halft = sub & 1;
  int rbase = halft * 304;
  if (tid < 16) ((uint4*)sS)[tid] = ((const uint4*)(sessb + (size_t)sb*D_))[tid];
  __syncthreads();
  for (int i = tid; i < 304; i += 256){
    int rr = rbase + i;
    int rrc = rr < 599 ? rr : 599;
    int nid;
    if (grp == 0){
      nid = neigh1[sb*600 + rrc];
    } else {
      int r2 = sb*1200 + (grp-1)*600 + rrc;
      nid = adj_all[(size_t)neigh1[r2 >> 1]*2 + (r2 & 1)];
    }
    nidS[i] = nid;
  }
  for (int i = tid; i < 2048; i += 256){
    int kt = i >> 9, ln = i & 63, q = (ln >> 4);
    uint4 w = w1f[i];
    uint4 sv = *(const uint4*)(sS + kt*32 + q*8);
    const ushort_t* wu = (const ushort_t*)&w;
    const ushort_t* su = (const ushort_t*)&sv;
    union { ushort_t u[8]; uint4 q4; } o;
    #pragma unroll
    for (int j = 0; j < 8; j++) o.u[j] = f2bf(bf2f(wu[j]) * bf2f(su[j]));
    frag[i] = o.q4;
  }
  __syncthreads();
  int lane = tid & 63, wave = tid >> 6;
  int m = lane & 15, q = lane >> 4;
  float w2v[8];
  #pragma unroll
  for (int t = 0; t < 8; t++) w2v[t] = bf2f(w2[16*t + m]);

  int tend = halft ? 38 : 19;
  int t0 = halft*19 + wave;
  uint4 cur[4];
  if (t0 < tend){
    int nid = nidS[t0*16 + m - rbase];
    const ushort_t* nrow = emb + (size_t)nid*D_;
    #pragma unroll
    for (int kt = 0; kt < 4; kt++)
      cur[kt] = *(const uint4*)(nrow + kt*32 + q*8);
  }
  for (int t = t0; t < tend; t += 4){
    uint4 nxt[4] = {};
    int tn = t + 4;
    if (tn < tend){
      int nid = nidS[tn*16 + m - rbase];
      const ushort_t* nrow = emb + (size_t)nid*D_;
      #pragma unroll
      for (int kt = 0; kt < 4; kt++)
        nxt[kt] = *(const uint4*)(nrow + kt*32 + q*8);
    }
    f32x4 acc[8];
    #pragma unroll
    for (int t8 = 0; t8 < 8; t8++) acc[t8] = (f32x4){0.f,0.f,0.f,0.f};
    #pragma unroll
    for (int kt = 0; kt < 4; kt++){
      union { uint4 q4; bf16x8 v; } af;
      af.q4 = cur[kt];
      #pragma unroll
      for (int t8 = 0; t8 < 8; t8++){
        union { uint4 q4; bf16x8 v; } bf;
        bf.q4 = frag[(kt*8 + t8)*64 + lane];
        acc[t8] = __builtin_amdgcn_mfma_f32_16x16x32_bf16(af.v, bf.v, acc[t8], 0, 0, 0);
      }
    }
    #pragma unroll
    for (int r = 0; r < 4; r++){
      float s = 0.f;
      #pragma unroll
      for (int t8 = 0; t8 < 8; t8++) s += leaky(acc[t8][r]) * w2v[t8];
      s += __shfl_xor(s, 1, 64);
      s += __shfl_xor(s, 2, 64);
      s += __shfl_xor(s, 4, 64);
      s += __shfl_xor(s, 8, 64);
      if (m == 0){
        int rw = t*16 + q*4 + r;
        if (rw < 600){
          int sidx = (grp == 0) ? (sb*600 + rw)
                                : (76800 + sb*1200 + (grp-1)*600 + rw);
          score[sidx] = s;
        }
      }
    }
    #pragma unroll
    for (int kt = 0; kt < 4; kt++) cur[kt] = nxt[kt];
  }
}

// ===========================================================================
// score2_c: hop-1 scores of out1 rows, session-organized, SW-pipelined. grid 512.
// ===========================================================================
__global__ __launch_bounds__(256) void score2_c(
    const ushort_t* __restrict__ sessb, const ushort_t* __restrict__ out1,
    const uint4* __restrict__ w1f, const ushort_t* __restrict__ w2,
    float* __restrict__ score)
{
  __shared__ uint4 bfrag[2048];
  __shared__ ushort_t sS[128];
  int blk = blockIdx.x, tid = threadIdx.x;
  int sb  = blk >> 2;
  int qtr = blk & 3;
  if (tid < 16) ((uint4*)sS)[tid] = ((const uint4*)(sessb + (size_t)sb*D_))[tid];
  __syncthreads();
  for (int i = tid; i < 2048; i += 256){
    int kt = i >> 9, ln = i & 63, q = (ln >> 4);
    uint4 w = w1f[i];
    uint4 sv = *(const uint4*)(sS + kt*32 + q*8);
    const ushort_t* wu = (const ushort_t*)&w;
    const ushort_t* su = (const ushort_t*)&sv;
    union { ushort_t u[8]; uint4 q4; } o;
    #pragma unroll
    for (int j = 0; j < 8; j++) o.u[j] = f2bf(bf2f(wu[j]) * bf2f(su[j]));
    bfrag[i] = o.q4;
  }
  __syncthreads();
  int lane = tid & 63, wave = tid >> 6;
  int m = lane & 15, q = lane >> 4;
  float w2v[8];
  #pragma unroll
  for (int t = 0; t < 8; t++) w2v[t] = bf2f(w2[16*t + m]);

  int t0 = qtr*10 + wave;
  int tend = (qtr*10 + 10 < 38) ? qtr*10 + 10 : 38;
  uint4 cur[4];
  if (t0 < tend){
    int rr = t0*16 + m;
    int rrc = rr < 599 ? rr : 599;
    const ushort_t* nrow = out1 + ((size_t)sb*600 + rrc)*D_;
    #pragma unroll
    for (int kt = 0; kt < 4; kt++)
      cur[kt] = *(const uint4*)(nrow + kt*32 + q*8);
  }
  for (int t = t0; t < tend; t += 4){
    uint4 nxt[4] = {};
    int tn = t + 4;
    if (tn < tend){
      int rr = tn*16 + m;
      int rrc = rr < 599 ? rr : 599;
      const ushort_t* nrow = out1 + ((size_t)sb*600 + rrc)*D_;
      #pragma unroll
      for (int kt = 0; kt < 4; kt++)
        nxt[kt] = *(const uint4*)(nrow + kt*32 + q*8);
    }
    f32x4 acc[8];
    #pragma unroll
    for (int t8 = 0; t8 < 8; t8++) acc[t8] = (f32x4){0.f,0.f,0.f,0.f};
    #pragma unroll
    for (int kt = 0; kt < 4; kt++){
      union { uint4 q4; bf16x8 v; } af;
      af.q4 = cur[kt];
      #pragma unroll
      for (int t8 = 0; t8 < 8; t8++){
        union { uint4 q4; bf16x8 v; } bf;
        bf.q4 = bfrag[(kt*8 + t8)*64 + lane];
        acc[t8] = __builtin_amdgcn_mfma_f32_16x16x32_bf16(af.v, bf.v, acc[t8], 0, 0, 0);
      }
    }
    #pragma unroll
    for (int r = 0; r < 4; r++){
      float s = 0.f;
      #pragma unroll
      for (int t8 = 0; t8 < 8; t8++) s += leaky(acc[t8][r]) * w2v[t8];
      s += __shfl_xor(s, 1, 64);
      s += __shfl_xor(s, 2, 64);
      s += __shfl_xor(s, 4, 64);
      s += __shfl_xor(s, 8, 64);
      if (m == 0){
        int rw = t*16 + q*4 + r;
        if (rw < 600) score[sb*600 + rw] = s;
      }
    }
    #pragma unroll
    for (int kt = 0; kt < 4; kt++) cur[kt] = nxt[kt];
  }
}

// ---- shared out helpers ---------------------------------------------------
template<int K>
__device__ __forceinline__ void softmaxK(const float* __restrict__ sc, float att[K]){
  float mx = -__builtin_inff();
  #pragma unroll
  for (int k = 0; k < K; k++){ att[k] = sc[k]; mx = fmaxf(mx, att[k]); }
  float s = 0.f;
  #pragma unroll
  for (int k = 0; k < K; k++){ att[k] = __expf(att[k] - mx); s += att[k]; }
  float inv = 1.f / s;
  #pragma unroll
  for (int k = 0; k < K; k++) att[k] *= inv;
}

template<int K>
__device__ __forceinline__ void out_tile(
    int lane, const uint4* __restrict__ afrag,
    const ushort_t* __restrict__ sptr, const ushort_t* const nptr[K],
    const float att[K], f32x4 acc[8]){
  int q = lane >> 4;
  #pragma unroll
  for (int kt = 0; kt < 8; kt++){
    union { ushort_t u[8]; uint4 q4; bf16x8 v; } bfr;
    if (kt < 4){
      bfr.q4 = *(const uint4*)(sptr + kt*32 + q*8);
    } else {
      float g[8] = {0,0,0,0,0,0,0,0};
      #pragma unroll
      for (int k = 0; k < K; k++){
        uint4 nv = *(const uint4*)(nptr[k] + (kt-4)*32 + q*8);
        const uint32_t* np = (const uint32_t*)&nv;
        #pragma unroll
        for (int p = 0; p < 4; p++){
          g[2*p]   = fmaf(att[k], __uint_as_float(np[p] << 16),         g[2*p]);
          g[2*p+1] = fmaf(att[k], __uint_as_float(np[p] & 0xffff0000u), g[2*p+1]);
        }
      }
      #pragma unroll
      for (int j = 0; j < 8; j++) bfr.u[j] = f2bf(g[j]);
    }
    #pragma unroll
    for (int t = 0; t < 8; t++){
      union { uint4 q4; bf16x8 v; } af;
      af.q4 = afrag[(kt*8 + t)*64 + lane];
      acc[t] = __builtin_amdgcn_mfma_f32_16x16x32_bf16(af.v, bfr.v, acc[t], 0, 0, 0);
    }
  }
}

// ===========================================================================
// gather_out: hop-0 out via precomputed T tables. One wave per out-row.
// ===========================================================================
__global__ __launch_bounds__(256) void gather_out(
    const int* __restrict__ idx, const int* __restrict__ nbr,
    const int* __restrict__ adj_all, const float* __restrict__ score,
    const ushort_t* __restrict__ Tt, const ushort_t* __restrict__ Tb,
    const ushort_t* __restrict__ bias,
    ushort_t* __restrict__ o0c, ushort_t* __restrict__ out1c,
    int nA50, int nTot, int scoreBbase)
{
  int row  = (blockIdx.x*256 + threadIdx.x) >> 6;
  int lane = threadIdx.x & 63;
  if (row >= nTot) return;
  row = __builtin_amdgcn_readfirstlane(row);
  float b0 = bf2f(bias[lane*2]), b1 = bf2f(bias[lane*2 + 1]);
  float acc0, acc1;
  ushort_t* dst;
  if (row < nA50){
    float att[12];
    softmaxK<12>(score + (size_t)row*12, att);
    uint32_t sv = *(const uint32_t*)(Tt + (size_t)idx[row]*D_ + lane*2);
    acc0 = __uint_as_float(sv << 16);
    acc1 = __uint_as_float(sv & 0xffff0000u);
    #pragma unroll
    for (int k = 0; k < 12; k++){
      uint32_t nv = *(const uint32_t*)(Tb + (size_t)nbr[row*12 + k]*D_ + lane*2);
      acc0 = fmaf(att[k], __uint_as_float(nv << 16),          acc0);
      acc1 = fmaf(att[k], __uint_as_float(nv & 0xffff0000u),  acc1);
    }
    dst = o0c + (size_t)row*D_;
  } else {
    int rB = row - nA50;
    float att[2];
    softmaxK<2>(score + scoreBbase + (size_t)rB*2, att);
    int self = nbr[rB];
    uint32_t sv = *(const uint32_t*)(Tt + (size_t)self*D_ + lane*2);
    acc0 = __uint_as_float(sv << 16);
    acc1 = __uint_as_float(sv & 0xffff0000u);
    #pragma unroll
    for (int k = 0; k < 2; k++){
      uint32_t nv = *(const uint32_t*)(Tb + (size_t)adj_all[(size_t)self*2 + k]*D_ + lane*2);
      acc0 = fmaf(att[k], __uint_as_float(nv << 16),          acc0);
      acc1 = fmaf(att[k], __uint_as_float(nv & 0xffff0000u),  acc1);
    }
    dst = out1c + (size_t)rB*D_;
  }
  union { ushort_t u[2]; uint32_t d; } pk;
  pk.u[0] = f2bf(fmaxf(acc0 + b0, 0.f));
  pk.u[1] = f2bf(fmaxf(acc1 + b1, 0.f));
  *(uint32_t*)(dst + lane*2) = pk.d;
}

// ===========================================================================
// out_mfma_c2: 128 thr, 32 rows/block -> 200 blocks (2x CU coverage vs 100)
// ===========================================================================
__global__ __launch_bounds__(128) void out_mfma_c2(
    const float* __restrict__ score, const ushort_t* __restrict__ out1,
    const ushort_t* __restrict__ selfsrc, const uint4* __restrict__ w3f,
    const ushort_t* __restrict__ bias,
    const ushort_t* __restrict__ addsrc, float* __restrict__ outf, int nrows){
  __shared__ uint4 afrag[4096];
  int tid = threadIdx.x;
  for (int i = tid; i < 4096; i += 128) afrag[i] = w3f[i];
  __syncthreads();
  int lane = tid & 63, wave = tid >> 6;   // 2 waves
  int mrow = lane & 15, q = lane >> 4;
  float bv[8][4];
  #pragma unroll
  for (int t = 0; t < 8; t++){
    const ushort_t* bp = bias + 16*t + q*4;
    #pragma unroll
    for (int r = 0; r < 4; r++) bv[t][r] = bf2f(bp[r]);
  }
  int row_base = blockIdx.x*32 + wave*16;
  int row = row_base + mrow;
  bool active = row < nrows;
  int rowc = active ? row : (nrows - 1);
  const ushort_t* sptr = selfsrc + (size_t)rowc*D_;
  const ushort_t* nptr[12];
  #pragma unroll
  for (int k = 0; k < 12; k++) nptr[k] = out1 + (size_t)(rowc*12 + k)*D_;
  float att[12];
  softmaxK<12>(score + (size_t)rowc*12, att);
  f32x4 acc[8];
  #pragma unroll
  for (int t = 0; t < 8; t++) acc[t] = (f32x4){0.f,0.f,0.f,0.f};
  out_tile<12>(lane, afrag, sptr, nptr, att, acc);
  if (active){
    #pragma unroll
    for (int t = 0; t < 8; t++){
      int col0 = 16*t + q*4;
      float v[4];
      const ushort_t* ap = addsrc + (size_t)row*D_ + col0;
      #pragma unroll
      for (int r = 0; r < 4; r++)
        v[r] = fmaxf(acc[t][r] + bv[t][r], 0.f) + bf2f(ap[r]);
      *(f32x4*)(outf + (size_t)row*D_ + col0) = (f32x4){v[0], v[1], v[2], v[3]};
    }
  }
}

// ===========================================================================
// Fallback kernels (round-0 proven direct path, used when ws too small)
// ===========================================================================
__global__ __launch_bounds__(256) void score_mfma_ab(
    const ushort_t* __restrict__ sessb, const ushort_t* __restrict__ emb,
    const int* __restrict__ neigh1, const int* __restrict__ adj_all,
    const uint4* __restrict__ w1f, const ushort_t* __restrict__ w2,
    float* __restrict__ score, int nA){
  __shared__ uint4 bfrag[2048];
  int tid = threadIdx.x;
  for (int i = tid; i < 2048; i += 256) bfrag[i] = w1f[i];
  __syncthreads();
  int lane = tid & 63, wave = tid >> 6;
  int m = lane & 15, q = lane >> 4;
  float w2v[8];
  #pragma unroll
  for (int t = 0; t < 8; t++) w2v[t] = bf2f(w2[16*t + m]);

  for (int it = 0; it < 2; it++){
    int row_base = blockIdx.x*128 + it*64 + wave*16;
    int row = row_base + m;
    const ushort_t* nrow; int b;
    if (row < nA){
      nrow = emb + (size_t)neigh1[row]*D_;
      b = row / 600;
    } else {
      int r2 = row - nA;
      nrow = emb + (size_t)adj_all[(size_t)neigh1[r2>>1]*2 + (r2&1)]*D_;
      b = r2 / 1200;
    }
    const ushort_t* srow = sessb + (size_t)b*D_;

    f32x4 acc[8];
    #pragma unroll
    for (int t = 0; t < 8; t++) acc[t] = (f32x4){0.f,0.f,0.f,0.f};
    #pragma unroll
    for (int kt = 0; kt < 4; kt++){
      uint4 nv = *(const uint4*)(nrow + kt*32 + q*8);
      uint4 sv = *(const uint4*)(srow + kt*32 + q*8);
      const uint32_t* np = (const uint32_t*)&nv;
      const uint32_t* sp = (const uint32_t*)&sv;
      union { ushort_t u[8]; bf16x8 v; } afr;
      #pragma unroll
      for (int p = 0; p < 4; p++){
        uint32_t n2 = np[p], s2 = sp[p];
        float a0 = __uint_as_float(n2 << 16)          * __uint_as_float(s2 << 16);
        float a1 = __uint_as_float(n2 & 0xffff0000u)  * __uint_as_float(s2 & 0xffff0000u);
        afr.u[2*p]   = f2bf(a0);
        afr.u[2*p+1] = f2bf(a1);
      }
      #pragma unroll
      for (int t = 0; t < 8; t++){
        union { uint4 q4; bf16x8 v; } bfr;
        bfr.q4 = bfrag[(kt*8 + t)*64 + lane];
        acc[t] = __builtin_amdgcn_mfma_f32_16x16x32_bf16(afr.v, bfr.v, acc[t], 0, 0, 0);
      }
    }
    #pragma unroll
    for (int r = 0; r < 4; r++){
      float s = 0.f;
      #pragma unroll
      for (int t = 0; t < 8; t++) s += leaky(acc[t][r]) * w2v[t];
      s += __shfl_xor(s, 1, 64);
      s += __shfl_xor(s, 2, 64);
      s += __shfl_xor(s, 4, 64);
      s += __shfl_xor(s, 8, 64);
      if (m == 0) score[row_base + q*4 + r] = s;
    }
  }
}

__global__ __launch_bounds__(256) void score_mfma_c(
    const ushort_t* __restrict__ sessb, const ushort_t* __restrict__ out1,
    const uint4* __restrict__ w1f, const ushort_t* __restrict__ w2,
    float* __restrict__ score){
  __shared__ uint4 bfrag[2048];
  int tid = threadIdx.x;
  for (int i = tid; i < 2048; i += 256) bfrag[i] = w1f[i];
  __syncthreads();
  int lane = tid & 63, wave = tid >> 6;
  int m = lane & 15, q = lane >> 4;
  float w2v[8];
  #pragma unroll
  for (int t = 0; t < 8; t++) w2v[t] = bf2f(w2[16*t + m]);
  for (int it = 0; it < 2; it++){
    int row_base = blockIdx.x*128 + it*64 + wave*16;
    int row = row_base + m;
    const ushort_t* nrow = out1 + (size_t)row*D_;
    int b = row / 600;
    const ushort_t* srow = sessb + (size_t)b*D_;
    f32x4 acc[8];
    #pragma unroll
    for (int t = 0; t < 8; t++) acc[t] = (f32x4){0.f,0.f,0.f,0.f};
    #pragma unroll
    for (int kt = 0; kt < 4; kt++){
      uint4 nv = *(const uint4*)(nrow + kt*32 + q*8);
      uint4 sv = *(const uint4*)(srow + kt*32 + q*8);
      const uint32_t* np = (const uint32_t*)&nv;
      const uint32_t* sp = (const uint32_t*)&sv;
      union { ushort_t u[8]; bf16x8 v; } afr;
      #pragma unroll
      for (int p = 0; p < 4; p++){
        uint32_t n2 = np[p], s2 = sp[p];
        float a0 = __uint_as_float(n2 << 16)          * __uint_as_float(s2 << 16);
        float a1 = __uint_as_float(n2 & 0xffff0000u)  * __uint_as_float(s2 & 0xffff0000u);
        afr.u[2*p]   = f2bf(a0);
        afr.u[2*p+1] = f2bf(a1);
      }
      #pragma unroll
      for (int t = 0; t < 8; t++){
        union { uint4 q4; bf16x8 v; } bfr;
        bfr.q4 = bfrag[(kt*8 + t)*64 + lane];
        acc[t] = __builtin_amdgcn_mfma_f32_16x16x32_bf16(afr.v, bfr.v, acc[t], 0, 0, 0);
      }
    }
    #pragma unroll
    for (int r = 0; r < 4; r++){
      float s = 0.f;
      #pragma unroll
      for (int t = 0; t < 8; t++) s += leaky(acc[t][r]) * w2v[t];
      s += __shfl_xor(s, 1, 64);
      s += __shfl_xor(s, 2, 64);
      s += __shfl_xor(s, 4, 64);
      s += __shfl_xor(s, 8, 64);
      if (m == 0) score[row_base + q*4 + r] = s;
    }
  }
}

__global__ __launch_bounds__(512) void out_mfma_ab(
    const float* __restrict__ score, const int* __restrict__ idx,
    const int* __restrict__ nbr, const int* __restrict__ adj_all,
    const ushort_t* __restrict__ emb, const uint4* __restrict__ w3f,
    const ushort_t* __restrict__ bias,
    ushort_t* __restrict__ o0c, ushort_t* __restrict__ out1c,
    int nA, int nTot, int scoreBbase){
  __shared__ uint4 afrag[4096];
  int tid = threadIdx.x;
  for (int i = tid; i < 4096; i += 512) afrag[i] = w3f[i];
  __syncthreads();
  int lane = tid & 63, wave = tid >> 6;
  int mrow = lane & 15, q = lane >> 4;
  float bv[8][4];
  #pragma unroll
  for (int t = 0; t < 8; t++){
    const ushort_t* bp = bias + 16*t + q*4;
    #pragma unroll
    for (int r = 0; r < 4; r++) bv[t][r] = bf2f(bp[r]);
  }
  int row_base = blockIdx.x*128 + wave*16;
  int row = row_base + mrow;
  bool active = row < nTot;
  int rowc = active ? row : (nTot - 1);
  bool isA = rowc < nA;
  f32x4 acc[8];
  #pragma unroll
  for (int t = 0; t < 8; t++) acc[t] = (f32x4){0.f,0.f,0.f,0.f};
  if (isA){
    const ushort_t* sptr = emb + (size_t)idx[rowc]*D_;
    const ushort_t* nptr[12];
    #pragma unroll
    for (int k = 0; k < 12; k++) nptr[k] = emb + (size_t)nbr[rowc*12 + k]*D_;
    float att[12];
    softmaxK<12>(score + (size_t)rowc*12, att);
    out_tile<12>(lane, afrag, sptr, nptr, att, acc);
  } else {
    int rB = rowc - nA;
    const ushort_t* sptr = emb + (size_t)nbr[rB]*D_;
    const ushort_t* nptr[2];
    #pragma unroll
    for (int k = 0; k < 2; k++) nptr[k] = emb + (size_t)adj_all[(size_t)nbr[rB]*2 + k]*D_;
    float att[2];
    softmaxK<2>(score + scoreBbase + (size_t)rB*2, att);
    out_tile<2>(lane, afrag, sptr, nptr, att, acc);
  }
  if (active){
    ushort_t* dst = isA ? (o0c + (size_t)row*D_) : (out1c + (size_t)(row - nA)*D_);
    #pragma unroll
    for (int t = 0; t < 8; t++){
      int col0 = 16*t + q*4;
      union { ushort_t u[4]; uint2 d2; } pk;
      #pragma unroll
      for (int r = 0; r < 4; r++) pk.u[r] = f2bf(fmaxf(acc[t][r] + bv[t][r], 0.f));
      *(uint2*)(dst + col0) = pk.d2;
    }
  }
}

__global__ __launch_bounds__(512) void out_mfma_c(
    const float* __restrict__ score, const ushort_t* __restrict__ out1,
    const ushort_t* __restrict__ selfsrc, const uint4* __restrict__ w3f,
    const ushort_t* __restrict__ bias,
    const ushort_t* __restrict__ addsrc, float* __restrict__ outf, int nrows){
  __shared__ uint4 afrag[4096];
  int tid = threadIdx.x;
  for (int i = tid; i < 4096; i += 512) afrag[i] = w3f[i];
  __syncthreads();
  int lane = tid & 63, wave = tid >> 6;
  int mrow = lane & 15, q = lane >> 4;
  float bv[8][4];
  #pragma unroll
  for (int t = 0; t < 8; t++){
    const ushort_t* bp = bias + 16*t + q*4;
    #pragma unroll
    for (int r = 0; r < 4; r++) bv[t][r] = bf2f(bp[r]);
  }
  int row_base = blockIdx.x*128 + wave*16;
  int row = row_base + mrow;
  bool active = row < nrows;
  int rowc = active ? row : (nrows - 1);
  const ushort_t* sptr = selfsrc + (size_t)rowc*D_;
  const ushort_t* nptr[12];
  #pragma unroll
  for (int k = 0; k < 12; k++) nptr[k] = out1 + (size_t)(rowc*12 + k)*D_;
  float att[12];
  softmaxK<12>(score + (size_t)rowc*12, att);
  f32x4 acc[8];
  #pragma unroll
  for (int t = 0; t < 8; t++) acc[t] = (f32x4){0.f,0.f,0.f,0.f};
  out_tile<12>(lane, afrag, sptr, nptr, att, acc);
  if (active){
    #pragma unroll
    for (int t = 0; t < 8; t++){
      int col0 = 16*t + q*4;
      float v[4];
      const ushort_t* ap = addsrc + (size_t)row*D_ + col0;
      #pragma unroll
      for (int r = 0; r < 4; r++)
        v[r] = fmaxf(acc[t][r] + bv[t][r], 0.f) + bf2f(ap[r]);
      *(f32x4*)(outf + (size_t)row*D_ + col0) = (f32x4){v[0], v[1], v[2], v[3]};
    }
  }
}

extern "C" void kernel_launch(void* const* d_in, const int* in_sizes, int n_in,
                              void* d_out, int out_size, void* d_ws, size_t ws_size,
                              hipStream_t stream) {
  const int* inputs    = (const int*)d_in[0];
  const int* adj       = (const int*)d_in[1];
  const int* mask_item = (const int*)d_in[2];
  const int* item      = (const int*)d_in[3];
  const int* first_adj = (const int*)d_in[4];    // neigh1 (B,600)
  const int* adj_all   = (const int*)d_in[5];    // (50000,2)

  char* ws = (char*)d_ws;
  size_t o = 0;
  ushort_t* emb_b  = (ushort_t*)(ws + o); o += 12800000;  // 50000*128
  ushort_t* alocb  = (ushort_t*)(ws + o); o += 1024;      // cvt segment (dead)
  ushort_t* gw1b   = (ushort_t*)(ws + o); o += 65536;     // cvt segment (dead)
  ushort_t* gw2b   = (ushort_t*)(ws + o); o += 512;       // 2*128
  ushort_t* gw3b   = (ushort_t*)(ws + o); o += 131072;    // cvt segment (dead)
  ushort_t* gbb    = (ushort_t*)(ws + o); o += 512;       // 2*128
  ushort_t* sessb  = (ushort_t*)(ws + o); o += 32768;     // 128*128
  ushort_t* hlb    = (ushort_t*)(ws + o); o += 1638400;   // 6400*128
  uint4*    w1f    = (uint4*)(ws + o);    o += 65536;
  uint4*    w3f    = (uint4*)(ws + o);    o += 131072;
  size_t fixed = o;
  (void)alocb; (void)gw1b; (void)gw3b;

  float* outp = (float*)d_out;

  const size_t TPATH_NEED = fixed + 2*(size_t)12800000       // Tt, Tb
                          + (size_t)128*153600               // out1c
                          + (size_t)128*12800                // o0c
                          + (size_t)3*128*600*4;             // score
  bool tpath = (ws_size >= TPATH_NEED);

  // ---- K1: local + sess + cvt + prep ----
  k1<<<K1_GRID_, 256, 0, stream>>>(
      inputs, adj, item, mask_item,
      d_in[6], d_in[7], d_in[8], d_in[9], d_in[10], d_in[11],
      emb_b, w1f, w3f, sessb, hlb, tpath ? 1 : 0);

  if (tpath){
    ushort_t* Tt    = (ushort_t*)(ws + o);  o += 12800000;
    ushort_t* Tb    = (ushort_t*)(ws + o);  o += 12800000;
    ushort_t* out1c = (ushort_t*)(ws + o);  o += (size_t)128*153600;
    ushort_t* o0c   = (ushort_t*)(ws + o);  o += (size_t)128*12800;
    float*    score = (float*)(ws + o);
    int nA600 = 128*600, nA50 = 128*50, nTot = 128*650;

    // K2: score2_ab (nid-prefetch + SW-pipeline) + tprep (4x row reuse)
    k2<<<K2_GRID_, 256, 0, stream>>>(d_in[6], emb_b, w3f, Tt, Tb,
                                     sessb, first_adj, adj_all,
                                     w1f, gw2b, score);
    // K3: gather hop-0 outputs
    gather_out<<<(nTot*64 + 255)/256, 256, 0, stream>>>(inputs, first_adj, adj_all, score,
                                                        Tt, Tb, gbb, o0c, out1c,
                                                        nA50, nTot, nA600);
    // K4: hop-1 scores (SW-pipelined)
    score2_c<<<512, 256, 0, stream>>>(sessb, out1c, w1f + 2048, gw2b + 128, score);
    // K5: hop-1 out + hl add (32 rows/block, 200 blocks)
    out_mfma_c2<<<(nA50 + 31)/32, 128, 0, stream>>>(score, out1c, o0c,
                                                    w3f + 4096, gbb + 128,
                                                    hlb, outp, nA50);
  } else {
    // ---- fallback: round-0 direct chunked path ----
    int CHB = 16;
    if      (ws_size >= fixed + (size_t)128*173600) CHB = 128;
    else if (ws_size >= fixed + (size_t)64 *173600) CHB = 64;
    else if (ws_size >= fixed + (size_t)32 *173600) CHB = 32;
    ushort_t* out1c = (ushort_t*)(ws + o);  o += (size_t)CHB*153600;
    ushort_t* o0c   = (ushort_t*)(ws + o);  o += (size_t)CHB*12800;
    float*    score = (float*)(ws + o);

    int nchunk = B_ / CHB;
    for (int c = 0; c < nchunk; c++){
      int b0 = c * CHB;
      const int* fadj  = first_adj + (size_t)b0 * 600;
      const ushort_t* sbc = sessb + (size_t)b0 * D_;
      ushort_t*  hlc   = hlb  + (size_t)b0 * 50 * D_;
      float*     outc  = outp + (size_t)b0 * 50 * D_;
      int nA600 = CHB*600, nA50 = CHB*50, nTot = CHB*650;

      score_mfma_ab<<<(3*nA600)/128, 256, 0, stream>>>(sbc, emb_b, fadj, adj_all,
                                                       w1f, gw2b, score, nA600);
      out_mfma_ab<<<(nTot + 127)/128, 512, 0, stream>>>(score, inputs + b0*50, fadj, adj_all,
                                                        emb_b, w3f, gbb, o0c, out1c,
                                                        nA50, nTot, nA600);
      score_mfma_c<<<nA600/128, 256, 0, stream>>>(sbc, out1c, w1f + 2048, gw2b + 128, score);
      out_mfma_c<<<(nA50 + 127)/128, 512, 0, stream>>>(score, out1c, o0c,
                                                       w3f + 4096, gbb + 128,
                                                       hlc, outc, nA50);
    }
  }
}

// Round 11
// 184.677 us; speedup vs baseline: 1.0322x; 1.0322x over previous
//
#include <hip/hip_runtime.h>
#include <stdint.h>

typedef unsigned short ushort_t;
typedef __attribute__((ext_vector_type(8))) short bf16x8;   // 4 VGPRs, 8 bf16
typedef __attribute__((ext_vector_type(4))) float f32x4;    // MFMA C/D

#define B_   128
#define S_   50
#define D_   128
#define ALPHA_ 0.2f

__device__ __forceinline__ float bf2f(ushort_t u){
  return __uint_as_float(((uint32_t)u) << 16);
}
__device__ __forceinline__ ushort_t f2bf(float f){
  uint32_t x = __float_as_uint(f);
  x = (x + 0x7fffu + ((x >> 16) & 1u)) >> 16;
  return (ushort_t)x;
}
__device__ __forceinline__ float leaky(float x){ return x >= 0.f ? x : ALPHA_*x; }

// per-block dtype detect: bf16-packed (1) vs f32 (0), from emb's first 64 words
__device__ __forceinline__ int detect_flag_block(const uint32_t* __restrict__ emb_raw){
  __shared__ int flg;
  if (threadIdx.x == 0){
    int ok = 1;
    for (int i = 0; i < 64; i++){
      uint32_t lo = emb_raw[i] & 0xffffu;
      uint32_t ex = (lo >> 7) & 0xFFu;
      if (!(lo == 0u || (ex >= 64u && ex <= 126u))) ok = 0;
    }
    flg = ok;
  }
  __syncthreads();
  return flg;
}

// ===========================================================================
// K1: cvt_all + prep_frags + sess + local, one launch (round-9 proven, 185.1).
// blocks: [0,512) local | [512,576) sess | [576,3750) cvt (16B/thr) |
//         [3750,3798) prep
// When flag==1 && skip_emb: cvt skips the emb segment (k2 reads p0 directly).
// ===========================================================================
#define NLOCAL_ 512
#define NSESS_  64
#define NCVT_   3174
#define NPREP_  48
#define CVT_BASE_   (NLOCAL_ + NSESS_)
#define PREP_BASE_  (CVT_BASE_ + NCVT_)
#define K1_GRID_    (PREP_BASE_ + NPREP_)

__global__ __launch_bounds__(256) void k1(
    const int* __restrict__ inputs, const int* __restrict__ adj,
    const int* __restrict__ item, const int* __restrict__ mask,
    const void* __restrict__ p0, const void* __restrict__ p1,
    const void* __restrict__ p2, const void* __restrict__ p3,
    const void* __restrict__ p4, const void* __restrict__ p5,
    ushort_t* __restrict__ emb_b, uint4* __restrict__ w1f, uint4* __restrict__ w3f,
    ushort_t* __restrict__ sessb, ushort_t* __restrict__ hlb, int skip_emb)
{
  int blk = blockIdx.x, tid = threadIdx.x;
  int flag = detect_flag_block((const uint32_t*)p0);

  if (blk < NLOCAL_){
    __shared__ ushort_t hS[64][136];
    __shared__ float    attS[16][68];
    __shared__ int      sids[64];
    __shared__ ushort_t alS[512];
    int b  = blk >> 2;
    int mi = blk & 3;
    if (tid < 64) sids[tid] = (tid < S_) ? inputs[b*S_ + tid] : 0;
    for (int i = tid; i < 512; i += 256)
      alS[i] = flag ? ((const ushort_t*)p1)[i] : f2bf(((const float*)p1)[i]);
    __syncthreads();
    if (flag){
      const ushort_t* e16 = (const ushort_t*)p0;
      for (int idx = tid; idx < 64*16; idx += 256){
        int j = idx >> 4, ch = idx & 15;
        uint4 v = {0u, 0u, 0u, 0u};
        if (j < S_) v = *(const uint4*)(e16 + (size_t)sids[j]*D_ + ch*8);
        *(uint4*)(&hS[j][ch*8]) = v;
      }
    } else {
      const float* ef = (const float*)p0;
      for (int idx = tid; idx < 64*32; idx += 256){
        int j = idx >> 5, ch = idx & 31;
        union { ushort_t u[4]; uint2 d2; } o;
        o.d2 = make_uint2(0u, 0u);
        if (j < S_){
          float4 v = *(const float4*)(ef + (size_t)sids[j]*D_ + ch*4);
          o.u[0]=f2bf(v.x); o.u[1]=f2bf(v.y); o.u[2]=f2bf(v.z); o.u[3]=f2bf(v.w);
        }
        *(uint2*)(&hS[j][ch*4]) = o.d2;
      }
    }
    for (int idx = tid; idx < 16*64; idx += 256)
      attS[idx >> 6][idx & 63] = -9.0e15f;
    __syncthreads();

    int lane = tid & 63, wv = tid >> 6;
    int q = lane >> 4, c = lane & 15;

    f32x4 Eacc[4];
    #pragma unroll
    for (int ni = 0; ni < 4; ni++) Eacc[ni] = (f32x4){0.f,0.f,0.f,0.f};
    #pragma unroll
    for (int kt = 0; kt < 4; kt++){
      uint4 av = *(const uint4*)(alS + wv*D_ + kt*32 + q*8);
      const uint32_t* ap = (const uint32_t*)&av;
      uint4 hv = *(const uint4*)(&hS[mi*16 + c][kt*32 + q*8]);
      const uint32_t* hp = (const uint32_t*)&hv;
      union { ushort_t u[8]; bf16x8 v; } afr;
      #pragma unroll
      for (int p = 0; p < 4; p++){
        float x0 = __uint_as_float(hp[p] << 16)         * __uint_as_float(ap[p] << 16);
        float x1 = __uint_as_float(hp[p] & 0xffff0000u) * __uint_as_float(ap[p] & 0xffff0000u);
        afr.u[2*p]   = f2bf(x0);
        afr.u[2*p+1] = f2bf(x1);
      }
      #pragma unroll
      for (int ni = 0; ni < 4; ni++){
        union { uint4 q4; bf16x8 v; } bfr;
        bfr.q4 = *(const uint4*)(&hS[ni*16 + c][kt*32 + q*8]);
        Eacc[ni] = __builtin_amdgcn_mfma_f32_16x16x32_bf16(afr.v, bfr.v, Eacc[ni], 0,0,0);
      }
    }
    const int* adjb = adj + (size_t)b*S_*S_;
    #pragma unroll
    for (int ni = 0; ni < 4; ni++){
      int j = ni*16 + c;
      #pragma unroll
      for (int r = 0; r < 4; r++){
        int i = mi*16 + q*4 + r;
        if (i < S_ && j < S_){
          int kk = adjb[i*S_ + j];
          if (kk == wv + 1) attS[q*4 + r][j] = leaky(Eacc[ni][r]);
        }
      }
    }
    __syncthreads();
    {
      int r  = tid >> 4;
      int cg = tid & 15;
      int i  = mi*16 + r;
      float v0 = attS[r][cg*4+0], v1 = attS[r][cg*4+1];
      float v2 = attS[r][cg*4+2], v3 = attS[r][cg*4+3];
      float mx = fmaxf(fmaxf(v0,v1), fmaxf(v2,v3));
      #pragma unroll
      for (int off = 1; off < 16; off <<= 1) mx = fmaxf(mx, __shfl_xor(mx, off, 16));
      float e0 = (cg*4+0 < S_) ? __expf(v0 - mx) : 0.f;
      float e1 = (cg*4+1 < S_) ? __expf(v1 - mx) : 0.f;
      float e2 = (cg*4+2 < S_) ? __expf(v2 - mx) : 0.f;
      float e3 = (cg*4+3 < S_) ? __expf(v3 - mx) : 0.f;
      float s = e0 + e1 + e2 + e3;
      #pragma unroll
      for (int off = 1; off < 16; off <<= 1) s += __shfl_xor(s, off, 16);
      float inv = (i < S_) ? 1.f / s : 0.f;
      attS[r][cg*4+0] = e0*inv;
      attS[r][cg*4+1] = e1*inv;
      attS[r][cg*4+2] = e2*inv;
      attS[r][cg*4+3] = e3*inv;
    }
    __syncthreads();
    f32x4 Pacc[2];
    Pacc[0] = (f32x4){0.f,0.f,0.f,0.f};
    Pacc[1] = (f32x4){0.f,0.f,0.f,0.f};
    #pragma unroll
    for (int kt = 0; kt < 2; kt++){
      union { ushort_t u[8]; bf16x8 v; } afr;
      const float* arow = &attS[c][kt*32 + q*8];
      #pragma unroll
      for (int j = 0; j < 8; j++) afr.u[j] = f2bf(arow[j]);
      #pragma unroll
      for (int nn = 0; nn < 2; nn++){
        int ni = 2*wv + nn;
        union { ushort_t u[8]; bf16x8 v; } bfr;
        #pragma unroll
        for (int jj = 0; jj < 8; jj++)
          bfr.u[jj] = hS[kt*32 + q*8 + jj][ni*16 + c];
        Pacc[nn] = __builtin_amdgcn_mfma_f32_16x16x32_bf16(afr.v, bfr.v, Pacc[nn], 0,0,0);
      }
    }
    #pragma unroll
    for (int nn = 0; nn < 2; nn++){
      int d = (2*wv + nn)*16 + c;
      #pragma unroll
      for (int r = 0; r < 4; r++){
        int i = mi*16 + q*4 + r;
        if (i < S_) hlb[((size_t)b*S_ + i)*D_ + d] = f2bf(Pacc[nn][r]);
      }
    }
  } else if (blk < CVT_BASE_){
    // ---- sess ----
    int b = (blk - NLOCAL_)*2 + (tid >> 7);
    int d = tid & 127;
    float acc = 0.f, den = 0.f;
    if (flag){
      const ushort_t* e16 = (const ushort_t*)p0;
      for (int s = 0; s < S_; s++){
        float fm = (float)mask[b*S_ + s];
        int id = item[b*S_ + s];
        acc += fm * bf2f(e16[(size_t)id*D_ + d]);
        den += fm;
      }
    } else {
      const float* ef = (const float*)p0;
      for (int s = 0; s < S_; s++){
        float fm = (float)mask[b*S_ + s];
        int id = item[b*S_ + s];
        acc += fm * ef[(size_t)id*D_ + d];
        den += fm;
      }
    }
    sessb[b*D_ + d] = f2bf(acc / den);
  } else if (blk < PREP_BASE_){
    // ---- cvt: six float tensors -> contiguous bf16, 16 B/thread ----
    const int seg_end[6] = {6400000, 6400512, 6433280, 6433536, 6499072, 6499328};
    int base = ((blk - CVT_BASE_)*256 + tid) * 8;
    if (base >= 6499328) return;
    if (flag && skip_emb && base < 6400000) return;   // emb read direct from p0
    int s = 0;
    while (base >= seg_end[s]) s++;
    int segbase = (s == 0) ? 0 : seg_end[s-1];
    const void* src = (s==0)?p0:(s==1)?p1:(s==2)?p2:(s==3)?p3:(s==4)?p4:p5;
    int off = base - segbase;
    union { ushort_t u[8]; uint4 q4; } o;
    if (flag){
      o.q4 = *(const uint4*)((const ushort_t*)src + off);
    } else {
      const float* fp = (const float*)src + off;
      float4 v0 = *(const float4*)(fp);
      float4 v1 = *(const float4*)(fp + 4);
      o.u[0]=f2bf(v0.x); o.u[1]=f2bf(v0.y); o.u[2]=f2bf(v0.z); o.u[3]=f2bf(v0.w);
      o.u[4]=f2bf(v1.x); o.u[5]=f2bf(v1.y); o.u[6]=f2bf(v1.z); o.u[7]=f2bf(v1.w);
    }
    *(uint4*)(emb_b + base) = o.q4;
  } else {
    // ---- prep_frags: w1/w3 -> pre-swizzled MFMA fragment buffers ----
    int id = (blk - PREP_BASE_)*256 + tid;
    if (id >= 12288) return;
    if (id < 4096){
      int h = id >> 11, i = id & 2047;
      int kt = i >> 9, rem = i & 511, t = rem >> 6, ln = rem & 63;
      int q = ln >> 4, c = ln & 15;
      union { ushort_t u[8]; uint4 q4; } e;
      #pragma unroll
      for (int j = 0; j < 8; j++){
        int idx = h*16384 + (32*kt + q*8 + j)*128 + 16*t + c;
        e.u[j] = flag ? ((const ushort_t*)p2)[idx] : f2bf(((const float*)p2)[idx]);
      }
      w1f[h*2048 + i] = e.q4;
    } else {
      int id2 = id - 4096;
      int h = id2 >> 12, i = id2 & 4095;
      int kt = i >> 9, rem = i & 511, t = rem >> 6, ln = rem & 63;
      int q = ln >> 4, c = ln & 15;
      union { ushort_t u[8]; uint4 q4; } e;
      #pragma unroll
      for (int j = 0; j < 8; j++){
        int idx = h*32768 + (32*kt + q*8 + j)*128 + 16*t + c;
        e.u[j] = flag ? ((const ushort_t*)p4)[idx] : f2bf(((const float*)p4)[idx]);
      }
      w3f[h*4096 + i] = e.q4;
    }
  }
}

// ===========================================================================
// K2: score2_ab (long blocks FIRST, nid-prefetch, SW-pipelined row gathers)
//     + tprep (4 row-tiles/stage).
// blocks [0,768): score2_ab | [768,1160): tprep (256 rows/block).
// emb operand selected per-block: p0 if bf16-packed, else emb_b.
// ===========================================================================
#define NT2SCORE_ 768
#define NT2TPREP_ 392
#define K2_GRID_  (NT2SCORE_ + NT2TPREP_)

__global__ __launch_bounds__(256) void k2(
    const void* __restrict__ p0, const ushort_t* __restrict__ emb_b,
    const uint4* __restrict__ w3f,
    ushort_t* __restrict__ Tt, ushort_t* __restrict__ Tb,
    const ushort_t* __restrict__ sessb,
    const int* __restrict__ neigh1, const int* __restrict__ adj_all,
    const uint4* __restrict__ w1f, const ushort_t* __restrict__ w2,
    float* __restrict__ score)
{
  __shared__ uint4 frag[2048];
  __shared__ ushort_t sS[128];
  __shared__ int nidS[304];
  int blk = blockIdx.x, tid = threadIdx.x;
  int flag = detect_flag_block((const uint32_t*)p0);
  const ushort_t* emb = flag ? (const ushort_t*)p0 : emb_b;

  if (blk >= NT2SCORE_){
    // ---- tprep: T = emb @ w3hop0; one half per block, 4 x 64 rows ----
    int tp   = blk - NT2SCORE_;
    int half = tp & 1;
    int rowbase0 = (tp >> 1) * 256;
    for (int i = tid; i < 2048; i += 256) frag[i] = w3f[half*2048 + i];
    __syncthreads();
    int lane = tid & 63, wave = tid >> 6;
    int m = lane & 15, q = lane >> 4;
    ushort_t* Tdst = half ? Tb : Tt;
    #pragma unroll
    for (int rit = 0; rit < 4; rit++){
      int row = rowbase0 + rit*64 + wave*16 + m;
      int rowc = row < 50000 ? row : 49999;
      f32x4 acc[8];
      #pragma unroll
      for (int t = 0; t < 8; t++) acc[t] = (f32x4){0.f,0.f,0.f,0.f};
      #pragma unroll
      for (int kt = 0; kt < 4; kt++){
        union { uint4 q4; bf16x8 v; } bfr;
        bfr.q4 = *(const uint4*)(emb + (size_t)rowc*D_ + kt*32 + q*8);
        #pragma unroll
        for (int t = 0; t < 8; t++){
          union { uint4 q4; bf16x8 v; } af;
          af.q4 = frag[(kt*8 + t)*64 + lane];
          acc[t] = __builtin_amdgcn_mfma_f32_16x16x32_bf16(af.v, bfr.v, acc[t], 0, 0, 0);
        }
      }
      if (row < 50000){
        ushort_t* dst = Tdst + (size_t)row*D_;
        #pragma unroll
        for (int t = 0; t < 8; t++){
          int col0 = 16*t + q*4;
          union { ushort_t u[4]; uint2 d2; } pk;
          #pragma unroll
          for (int r = 0; r < 4; r++) pk.u[r] = f2bf(acc[t][r]);
          *(uint2*)(dst + col0) = pk.d2;
        }
      }
    }
    return;
  }

  // ---- score2_ab: sess folded into w1-frag, nids prefetched to LDS,
  //      row gathers software-pipelined one tile ahead ----
  int b2  = blk;
  int sb  = b2 / 6;
  int sub = b2 - sb*6;
  int grp = sub >> 1;
  int halft = sub & 1;
  int rbase = halft * 304;
  if (tid < 16) ((uint4*)sS)[tid] = ((const uint4*)(sessb + (size_t)sb*D_))[tid];
  __syncthreads();
  for (int i = tid; i < 304; i += 256){
    int rr = rbase + i;
    int rrc = rr < 599 ? rr : 599;
    int nid;
    if (grp == 0){
      nid = neigh1[sb*600 + rrc];
    } else {
      int r2 = sb*1200 + (grp-1)*600 + rrc;
      nid = adj_all[(size_t)neigh1[r2 >> 1]*2 + (r2 & 1)];
    }
    nidS[i] = nid;
  }
  for (int i = tid; i < 2048; i += 256){
    int kt = i >> 9, ln = i & 63, q = (ln >> 4);
    uint4 w = w1f[i];
    uint4 sv = *(const uint4*)(sS + kt*32 + q*8);
    const ushort_t* wu = (const ushort_t*)&w;
    const ushort_t* su = (const ushort_t*)&sv;
    union { ushort_t u[8]; uint4 q4; } o;
    #pragma unroll
    for (int j = 0; j < 8; j++) o.u[j] = f2bf(bf2f(wu[j]) * bf2f(su[j]));
    frag[i] = o.q4;
  }
  __syncthreads();
  int lane = tid & 63, wave = tid >> 6;
  int m = lane & 15, q = lane >> 4;
  float w2v[8];
  #pragma unroll
  for (int t = 0; t < 8; t++) w2v[t] = bf2f(w2[16*t + m]);

  int tend = halft ? 38 : 19;
  int t0 = halft*19 + wave;
  uint4 cur[4];
  if (t0 < tend){
    int nid = nidS[t0*16 + m - rbase];
    const ushort_t* nrow = emb + (size_t)nid*D_;
    #pragma unroll
    for (int kt = 0; kt < 4; kt++)
      cur[kt] = *(const uint4*)(nrow + kt*32 + q*8);
  }
  for (int t = t0; t < tend; t += 4){
    uint4 nxt[4] = {};
    int tn = t + 4;
    if (tn < tend){
      int nid = nidS[tn*16 + m - rbase];
      const ushort_t* nrow = emb + (size_t)nid*D_;
      #pragma unroll
      for (int kt = 0; kt < 4; kt++)
        nxt[kt] = *(const uint4*)(nrow + kt*32 + q*8);
    }
    f32x4 acc[8];
    #pragma unroll
    for (int t8 = 0; t8 < 8; t8++) acc[t8] = (f32x4){0.f,0.f,0.f,0.f};
    #pragma unroll
    for (int kt = 0; kt < 4; kt++){
      union { uint4 q4; bf16x8 v; } af;
      af.q4 = cur[kt];
      #pragma unroll
      for (int t8 = 0; t8 < 8; t8++){
        union { uint4 q4; bf16x8 v; } bf;
        bf.q4 = frag[(kt*8 + t8)*64 + lane];
        acc[t8] = __builtin_amdgcn_mfma_f32_16x16x32_bf16(af.v, bf.v, acc[t8], 0, 0, 0);
      }
    }
    #pragma unroll
    for (int r = 0; r < 4; r++){
      float s = 0.f;
      #pragma unroll
      for (int t8 = 0; t8 < 8; t8++) s += leaky(acc[t8][r]) * w2v[t8];
      s += __shfl_xor(s, 1, 64);
      s += __shfl_xor(s, 2, 64);
      s += __shfl_xor(s, 4, 64);
      s += __shfl_xor(s, 8, 64);
      if (m == 0){
        int rw = t*16 + q*4 + r;
        if (rw < 600){
          int sidx = (grp == 0) ? (sb*600 + rw)
                                : (76800 + sb*1200 + (grp-1)*600 + rw);
          score[sidx] = s;
        }
      }
    }
    #pragma unroll
    for (int kt = 0; kt < 4; kt++) cur[kt] = nxt[kt];
  }
}

// ===========================================================================
// score2_c: hop-1 scores of out1 rows, session-organized, SW-pipelined. grid 512.
// ===========================================================================
__global__ __launch_bounds__(256) void score2_c(
    const ushort_t* __restrict__ sessb, const ushort_t* __restrict__ out1,
    const uint4* __restrict__ w1f, const ushort_t* __restrict__ w2,
    float* __restrict__ score)
{
  __shared__ uint4 bfrag[2048];
  __shared__ ushort_t sS[128];
  int blk = blockIdx.x, tid = threadIdx.x;
  int sb  = blk >> 2;
  int qtr = blk & 3;
  if (tid < 16) ((uint4*)sS)[tid] = ((const uint4*)(sessb + (size_t)sb*D_))[tid];
  __syncthreads();
  for (int i = tid; i < 2048; i += 256){
    int kt = i >> 9, ln = i & 63, q = (ln >> 4);
    uint4 w = w1f[i];
    uint4 sv = *(const uint4*)(sS + kt*32 + q*8);
    const ushort_t* wu = (const ushort_t*)&w;
    const ushort_t* su = (const ushort_t*)&sv;
    union { ushort_t u[8]; uint4 q4; } o;
    #pragma unroll
    for (int j = 0; j < 8; j++) o.u[j] = f2bf(bf2f(wu[j]) * bf2f(su[j]));
    bfrag[i] = o.q4;
  }
  __syncthreads();
  int lane = tid & 63, wave = tid >> 6;
  int m = lane & 15, q = lane >> 4;
  float w2v[8];
  #pragma unroll
  for (int t = 0; t < 8; t++) w2v[t] = bf2f(w2[16*t + m]);

  int t0 = qtr*10 + wave;
  int tend = (qtr*10 + 10 < 38) ? qtr*10 + 10 : 38;
  uint4 cur[4];
  if (t0 < tend){
    int rr = t0*16 + m;
    int rrc = rr < 599 ? rr : 599;
    const ushort_t* nrow = out1 + ((size_t)sb*600 + rrc)*D_;
    #pragma unroll
    for (int kt = 0; kt < 4; kt++)
      cur[kt] = *(const uint4*)(nrow + kt*32 + q*8);
  }
  for (int t = t0; t < tend; t += 4){
    uint4 nxt[4] = {};
    int tn = t + 4;
    if (tn < tend){
      int rr = tn*16 + m;
      int rrc = rr < 599 ? rr : 599;
      const ushort_t* nrow = out1 + ((size_t)sb*600 + rrc)*D_;
      #pragma unroll
      for (int kt = 0; kt < 4; kt++)
        nxt[kt] = *(const uint4*)(nrow + kt*32 + q*8);
    }
    f32x4 acc[8];
    #pragma unroll
    for (int t8 = 0; t8 < 8; t8++) acc[t8] = (f32x4){0.f,0.f,0.f,0.f};
    #pragma unroll
    for (int kt = 0; kt < 4; kt++){
      union { uint4 q4; bf16x8 v; } af;
      af.q4 = cur[kt];
      #pragma unroll
      for (int t8 = 0; t8 < 8; t8++){
        union { uint4 q4; bf16x8 v; } bf;
        bf.q4 = bfrag[(kt*8 + t8)*64 + lane];
        acc[t8] = __builtin_amdgcn_mfma_f32_16x16x32_bf16(af.v, bf.v, acc[t8], 0, 0, 0);
      }
    }
    #pragma unroll
    for (int r = 0; r < 4; r++){
      float s = 0.f;
      #pragma unroll
      for (int t8 = 0; t8 < 8; t8++) s += leaky(acc[t8][r]) * w2v[t8];
      s += __shfl_xor(s, 1, 64);
      s += __shfl_xor(s, 2, 64);
      s += __shfl_xor(s, 4, 64);
      s += __shfl_xor(s, 8, 64);
      if (m == 0){
        int rw = t*16 + q*4 + r;
        if (rw < 600) score[sb*600 + rw] = s;
      }
    }
    #pragma unroll
    for (int kt = 0; kt < 4; kt++) cur[kt] = nxt[kt];
  }
}

// ---- shared out helpers ---------------------------------------------------
template<int K>
__device__ __forceinline__ void softmaxK(const float* __restrict__ sc, float att[K]){
  float mx = -__builtin_inff();
  #pragma unroll
  for (int k = 0; k < K; k++){ att[k] = sc[k]; mx = fmaxf(mx, att[k]); }
  float s = 0.f;
  #pragma unroll
  for (int k = 0; k < K; k++){ att[k] = __expf(att[k] - mx); s += att[k]; }
  float inv = 1.f / s;
  #pragma unroll
  for (int k = 0; k < K; k++) att[k] *= inv;
}

template<int K>
__device__ __forceinline__ void out_tile(
    int lane, const uint4* __restrict__ afrag,
    const ushort_t* __restrict__ sptr, const ushort_t* const nptr[K],
    const float att[K], f32x4 acc[8]){
  int q = lane >> 4;
  #pragma unroll
  for (int kt = 0; kt < 8; kt++){
    union { ushort_t u[8]; uint4 q4; bf16x8 v; } bfr;
    if (kt < 4){
      bfr.q4 = *(const uint4*)(sptr + kt*32 + q*8);
    } else {
      float g[8] = {0,0,0,0,0,0,0,0};
      #pragma unroll
      for (int k = 0; k < K; k++){
        uint4 nv = *(const uint4*)(nptr[k] + (kt-4)*32 + q*8);
        const uint32_t* np = (const uint32_t*)&nv;
        #pragma unroll
        for (int p = 0; p < 4; p++){
          g[2*p]   = fmaf(att[k], __uint_as_float(np[p] << 16),         g[2*p]);
          g[2*p+1] = fmaf(att[k], __uint_as_float(np[p] & 0xffff0000u), g[2*p+1]);
        }
      }
      #pragma unroll
      for (int j = 0; j < 8; j++) bfr.u[j] = f2bf(g[j]);
    }
    #pragma unroll
    for (int t = 0; t < 8; t++){
      union { uint4 q4; bf16x8 v; } af;
      af.q4 = afrag[(kt*8 + t)*64 + lane];
      acc[t] = __builtin_amdgcn_mfma_f32_16x16x32_bf16(af.v, bfr.v, acc[t], 0, 0, 0);
    }
  }
}

// ===========================================================================
// gather_out: hop-0 out via precomputed T tables. One wave per out-row.
// ===========================================================================
__global__ __launch_bounds__(256) void gather_out(
    const int* __restrict__ idx, const int* __restrict__ nbr,
    const int* __restrict__ adj_all, const float* __restrict__ score,
    const ushort_t* __restrict__ Tt, const ushort_t* __restrict__ Tb,
    const ushort_t* __restrict__ bias,
    ushort_t* __restrict__ o0c, ushort_t* __restrict__ out1c,
    int nA50, int nTot, int scoreBbase)
{
  int row  = (blockIdx.x*256 + threadIdx.x) >> 6;
  int lane = threadIdx.x & 63;
  if (row >= nTot) return;
  row = __builtin_amdgcn_readfirstlane(row);
  float b0 = bf2f(bias[lane*2]), b1 = bf2f(bias[lane*2 + 1]);
  float acc0, acc1;
  ushort_t* dst;
  if (row < nA50){
    float att[12];
    softmaxK<12>(score + (size_t)row*12, att);
    uint32_t sv = *(const uint32_t*)(Tt + (size_t)idx[row]*D_ + lane*2);
    acc0 = __uint_as_float(sv << 16);
    acc1 = __uint_as_float(sv & 0xffff0000u);
    #pragma unroll
    for (int k = 0; k < 12; k++){
      uint32_t nv = *(const uint32_t*)(Tb + (size_t)nbr[row*12 + k]*D_ + lane*2);
      acc0 = fmaf(att[k], __uint_as_float(nv << 16),          acc0);
      acc1 = fmaf(att[k], __uint_as_float(nv & 0xffff0000u),  acc1);
    }
    dst = o0c + (size_t)row*D_;
  } else {
    int rB = row - nA50;
    float att[2];
    softmaxK<2>(score + scoreBbase + (size_t)rB*2, att);
    int self = nbr[rB];
    uint32_t sv = *(const uint32_t*)(Tt + (size_t)self*D_ + lane*2);
    acc0 = __uint_as_float(sv << 16);
    acc1 = __uint_as_float(sv & 0xffff0000u);
    #pragma unroll
    for (int k = 0; k < 2; k++){
      uint32_t nv = *(const uint32_t*)(Tb + (size_t)adj_all[(size_t)self*2 + k]*D_ + lane*2);
      acc0 = fmaf(att[k], __uint_as_float(nv << 16),          acc0);
      acc1 = fmaf(att[k], __uint_as_float(nv & 0xffff0000u),  acc1);
    }
    dst = out1c + (size_t)rB*D_;
  }
  union { ushort_t u[2]; uint32_t d; } pk;
  pk.u[0] = f2bf(fmaxf(acc0 + b0, 0.f));
  pk.u[1] = f2bf(fmaxf(acc1 + b1, 0.f));
  *(uint32_t*)(dst + lane*2) = pk.d;
}

// ===========================================================================
// out_mfma_c2: 256 thr, 64 rows/block -> 100 blocks (round-9 proven)
// ===========================================================================
__global__ __launch_bounds__(256) void out_mfma_c2(
    const float* __restrict__ score, const ushort_t* __restrict__ out1,
    const ushort_t* __restrict__ selfsrc, const uint4* __restrict__ w3f,
    const ushort_t* __restrict__ bias,
    const ushort_t* __restrict__ addsrc, float* __restrict__ outf, int nrows){
  __shared__ uint4 afrag[4096];
  int tid = threadIdx.x;
  for (int i = tid; i < 4096; i += 256) afrag[i] = w3f[i];
  __syncthreads();
  int lane = tid & 63, wave = tid >> 6;
  int mrow = lane & 15, q = lane >> 4;
  float bv[8][4];
  #pragma unroll
  for (int t = 0; t < 8; t++){
    const ushort_t* bp = bias + 16*t + q*4;
    #pragma unroll
    for (int r = 0; r < 4; r++) bv[t][r] = bf2f(bp[r]);
  }
  int row_base = blockIdx.x*64 + wave*16;
  int row = row_base + mrow;
  bool active = row < nrows;
  int rowc = active ? row : (nrows - 1);
  const ushort_t* sptr = selfsrc + (size_t)rowc*D_;
  const ushort_t* nptr[12];
  #pragma unroll
  for (int k = 0; k < 12; k++) nptr[k] = out1 + (size_t)(rowc*12 + k)*D_;
  float att[12];
  softmaxK<12>(score + (size_t)rowc*12, att);
  f32x4 acc[8];
  #pragma unroll
  for (int t = 0; t < 8; t++) acc[t] = (f32x4){0.f,0.f,0.f,0.f};
  out_tile<12>(lane, afrag, sptr, nptr, att, acc);
  if (active){
    #pragma unroll
    for (int t = 0; t < 8; t++){
      int col0 = 16*t + q*4;
      float v[4];
      const ushort_t* ap = addsrc + (size_t)row*D_ + col0;
      #pragma unroll
      for (int r = 0; r < 4; r++)
        v[r] = fmaxf(acc[t][r] + bv[t][r], 0.f) + bf2f(ap[r]);
      *(f32x4*)(outf + (size_t)row*D_ + col0) = (f32x4){v[0], v[1], v[2], v[3]};
    }
  }
}

// ===========================================================================
// Fallback kernels (round-0 proven direct path, used when ws too small)
// ===========================================================================
__global__ __launch_bounds__(256) void score_mfma_ab(
    const ushort_t* __restrict__ sessb, const ushort_t* __restrict__ emb,
    const int* __restrict__ neigh1, const int* __restrict__ adj_all,
    const uint4* __restrict__ w1f, const ushort_t* __restrict__ w2,
    float* __restrict__ score, int nA){
  __shared__ uint4 bfrag[2048];
  int tid = threadIdx.x;
  for (int i = tid; i < 2048; i += 256) bfrag[i] = w1f[i];
  __syncthreads();
  int lane = tid & 63, wave = tid >> 6;
  int m = lane & 15, q = lane >> 4;
  float w2v[8];
  #pragma unroll
  for (int t = 0; t < 8; t++) w2v[t] = bf2f(w2[16*t + m]);

  for (int it = 0; it < 2; it++){
    int row_base = blockIdx.x*128 + it*64 + wave*16;
    int row = row_base + m;
    const ushort_t* nrow; int b;
    if (row < nA){
      nrow = emb + (size_t)neigh1[row]*D_;
      b = row / 600;
    } else {
      int r2 = row - nA;
      nrow = emb + (size_t)adj_all[(size_t)neigh1[r2>>1]*2 + (r2&1)]*D_;
      b = r2 / 1200;
    }
    const ushort_t* srow = sessb + (size_t)b*D_;

    f32x4 acc[8];
    #pragma unroll
    for (int t = 0; t < 8; t++) acc[t] = (f32x4){0.f,0.f,0.f,0.f};
    #pragma unroll
    for (int kt = 0; kt < 4; kt++){
      uint4 nv = *(const uint4*)(nrow + kt*32 + q*8);
      uint4 sv = *(const uint4*)(srow + kt*32 + q*8);
      const uint32_t* np = (const uint32_t*)&nv;
      const uint32_t* sp = (const uint32_t*)&sv;
      union { ushort_t u[8]; bf16x8 v; } afr;
      #pragma unroll
      for (int p = 0; p < 4; p++){
        uint32_t n2 = np[p], s2 = sp[p];
        float a0 = __uint_as_float(n2 << 16)          * __uint_as_float(s2 << 16);
        float a1 = __uint_as_float(n2 & 0xffff0000u)  * __uint_as_float(s2 & 0xffff0000u);
        afr.u[2*p]   = f2bf(a0);
        afr.u[2*p+1] = f2bf(a1);
      }
      #pragma unroll
      for (int t = 0; t < 8; t++){
        union { uint4 q4; bf16x8 v; } bfr;
        bfr.q4 = bfrag[(kt*8 + t)*64 + lane];
        acc[t] = __builtin_amdgcn_mfma_f32_16x16x32_bf16(afr.v, bfr.v, acc[t], 0, 0, 0);
      }
    }
    #pragma unroll
    for (int r = 0; r < 4; r++){
      float s = 0.f;
      #pragma unroll
      for (int t = 0; t < 8; t++) s += leaky(acc[t][r]) * w2v[t];
      s += __shfl_xor(s, 1, 64);
      s += __shfl_xor(s, 2, 64);
      s += __shfl_xor(s, 4, 64);
      s += __shfl_xor(s, 8, 64);
      if (m == 0) score[row_base + q*4 + r] = s;
    }
  }
}

__global__ __launch_bounds__(256) void score_mfma_c(
    const ushort_t* __restrict__ sessb, const ushort_t* __restrict__ out1,
    const uint4* __restrict__ w1f, const ushort_t* __restrict__ w2,
    float* __restrict__ score){
  __shared__ uint4 bfrag[2048];
  int tid = threadIdx.x;
  for (int i = tid; i < 2048; i += 256) bfrag[i] = w1f[i];
  __syncthreads();
  int lane = tid & 63, wave = tid >> 6;
  int m = lane & 15, q = lane >> 4;
  float w2v[8];
  #pragma unroll
  for (int t = 0; t < 8; t++) w2v[t] = bf2f(w2[16*t + m]);
  for (int it = 0; it < 2; it++){
    int row_base = blockIdx.x*128 + it*64 + wave*16;
    int row = row_base + m;
    const ushort_t* nrow = out1 + (size_t)row*D_;
    int b = row / 600;
    const ushort_t* srow = sessb + (size_t)b*D_;
    f32x4 acc[8];
    #pragma unroll
    for (int t = 0; t < 8; t++) acc[t] = (f32x4){0.f,0.f,0.f,0.f};
    #pragma unroll
    for (int kt = 0; kt < 4; kt++){
      uint4 nv = *(const uint4*)(nrow + kt*32 + q*8);
      uint4 sv = *(const uint4*)(srow + kt*32 + q*8);
      const uint32_t* np = (const uint32_t*)&nv;
      const uint32_t* sp = (const uint32_t*)&sv;
      union { ushort_t u[8]; bf16x8 v; } afr;
      #pragma unroll
      for (int p = 0; p < 4; p++){
        uint32_t n2 = np[p], s2 = sp[p];
        float a0 = __uint_as_float(n2 << 16)          * __uint_as_float(s2 << 16);
        float a1 = __uint_as_float(n2 & 0xffff0000u)  * __uint_as_float(s2 & 0xffff0000u);
        afr.u[2*p]   = f2bf(a0);
        afr.u[2*p+1] = f2bf(a1);
      }
      #pragma unroll
      for (int t = 0; t < 8; t++){
        union { uint4 q4; bf16x8 v; } bfr;
        bfr.q4 = bfrag[(kt*8 + t)*64 + lane];
        acc[t] = __builtin_amdgcn_mfma_f32_16x16x32_bf16(afr.v, bfr.v, acc[t], 0, 0, 0);
      }
    }
    #pragma unroll
    for (int r = 0; r < 4; r++){
      float s = 0.f;
      #pragma unroll
      for (int t = 0; t < 8; t++) s += leaky(acc[t][r]) * w2v[t];
      s += __shfl_xor(s, 1, 64);
      s += __shfl_xor(s, 2, 64);
      s += __shfl_xor(s, 4, 64);
      s += __shfl_xor(s, 8, 64);
      if (m == 0) score[row_base + q*4 + r] = s;
    }
  }
}

__global__ __launch_bounds__(512) void out_mfma_ab(
    const float* __restrict__ score, const int* __restrict__ idx,
    const int* __restrict__ nbr, const int* __restrict__ adj_all,
    const ushort_t* __restrict__ emb, const uint4* __restrict__ w3f,
    const ushort_t* __restrict__ bias,
    ushort_t* __restrict__ o0c, ushort_t* __restrict__ out1c,
    int nA, int nTot, int scoreBbase){
  __shared__ uint4 afrag[4096];
  int tid = threadIdx.x;
  for (int i = tid; i < 4096; i += 512) afrag[i] = w3f[i];
  __syncthreads();
  int lane = tid & 63, wave = tid >> 6;
  int mrow = lane & 15, q = lane >> 4;
  float bv[8][4];
  #pragma unroll
  for (int t = 0; t < 8; t++){
    const ushort_t* bp = bias + 16*t + q*4;
    #pragma unroll
    for (int r = 0; r < 4; r++) bv[t][r] = bf2f(bp[r]);
  }
  int row_base = blockIdx.x*128 + wave*16;
  int row = row_base + mrow;
  bool active = row < nTot;
  int rowc = active ? row : (nTot - 1);
  bool isA = rowc < nA;
  f32x4 acc[8];
  #pragma unroll
  for (int t = 0; t < 8; t++) acc[t] = (f32x4){0.f,0.f,0.f,0.f};
  if (isA){
    const ushort_t* sptr = emb + (size_t)idx[rowc]*D_;
    const ushort_t* nptr[12];
    #pragma unroll
    for (int k = 0; k < 12; k++) nptr[k] = emb + (size_t)nbr[rowc*12 + k]*D_;
    float att[12];
    softmaxK<12>(score + (size_t)rowc*12, att);
    out_tile<12>(lane, afrag, sptr, nptr, att, acc);
  } else {
    int rB = rowc - nA;
    const ushort_t* sptr = emb + (size_t)nbr[rB]*D_;
    const ushort_t* nptr[2];
    #pragma unroll
    for (int k = 0; k < 2; k++) nptr[k] = emb + (size_t)adj_all[(size_t)nbr[rB]*2 + k]*D_;
    float att[2];
    softmaxK<2>(score + scoreBbase + (size_t)rB*2, att);
    out_tile<2>(lane, afrag, sptr, nptr, att, acc);
  }
  if (active){
    ushort_t* dst = isA ? (o0c + (size_t)row*D_) : (out1c + (size_t)(row - nA)*D_);
    #pragma unroll
    for (int t = 0; t < 8; t++){
      int col0 = 16*t + q*4;
      union { ushort_t u[4]; uint2 d2; } pk;
      #pragma unroll
      for (int r = 0; r < 4; r++) pk.u[r] = f2bf(fmaxf(acc[t][r] + bv[t][r], 0.f));
      *(uint2*)(dst + col0) = pk.d2;
    }
  }
}

__global__ __launch_bounds__(512) void out_mfma_c(
    const float* __restrict__ score, const ushort_t* __restrict__ out1,
    const ushort_t* __restrict__ selfsrc, const uint4* __restrict__ w3f,
    const ushort_t* __restrict__ bias,
    const ushort_t* __restrict__ addsrc, float* __restrict__ outf, int nrows){
  __shared__ uint4 afrag[4096];
  int tid = threadIdx.x;
  for (int i = tid; i < 4096; i += 512) afrag[i] = w3f[i];
  __syncthreads();
  int lane = tid & 63, wave = tid >> 6;
  int mrow = lane & 15, q = lane >> 4;
  float bv[8][4];
  #pragma unroll
  for (int t = 0; t < 8; t++){
    const ushort_t* bp = bias + 16*t + q*4;
    #pragma unroll
    for (int r = 0; r < 4; r++) bv[t][r] = bf2f(bp[r]);
  }
  int row_base = blockIdx.x*128 + wave*16;
  int row = row_base + mrow;
  bool active = row < nrows;
  int rowc = active ? row : (nrows - 1);
  const ushort_t* sptr = selfsrc + (size_t)rowc*D_;
  const ushort_t* nptr[12];
  #pragma unroll
  for (int k = 0; k < 12; k++) nptr[k] = out1 + (size_t)(rowc*12 + k)*D_;
  float att[12];
  softmaxK<12>(score + (size_t)rowc*12, att);
  f32x4 acc[8];
  #pragma unroll
  for (int t = 0; t < 8; t++) acc[t] = (f32x4){0.f,0.f,0.f,0.f};
  out_tile<12>(lane, afrag, sptr, nptr, att, acc);
  if (active){
    #pragma unroll
    for (int t = 0; t < 8; t++){
      int col0 = 16*t + q*4;
      float v[4];
      const ushort_t* ap = addsrc + (size_t)row*D_ + col0;
      #pragma unroll
      for (int r = 0; r < 4; r++)
        v[r] = fmaxf(acc[t][r] + bv[t][r], 0.f) + bf2f(ap[r]);
      *(f32x4*)(outf + (size_t)row*D_ + col0) = (f32x4){v[0], v[1], v[2], v[3]};
    }
  }
}

extern "C" void kernel_launch(void* const* d_in, const int* in_sizes, int n_in,
                              void* d_out, int out_size, void* d_ws, size_t ws_size,
                              hipStream_t stream) {
  const int* inputs    = (const int*)d_in[0];
  const int* adj       = (const int*)d_in[1];
  const int* mask_item = (const int*)d_in[2];
  const int* item      = (const int*)d_in[3];
  const int* first_adj = (const int*)d_in[4];    // neigh1 (B,600)
  const int* adj_all   = (const int*)d_in[5];    // (50000,2)

  char* ws = (char*)d_ws;
  size_t o = 0;
  ushort_t* emb_b  = (ushort_t*)(ws + o); o += 12800000;  // 50000*128
  ushort_t* alocb  = (ushort_t*)(ws + o); o += 1024;      // cvt segment (dead)
  ushort_t* gw1b   = (ushort_t*)(ws + o); o += 65536;     // cvt segment (dead)
  ushort_t* gw2b   = (ushort_t*)(ws + o); o += 512;       // 2*128
  ushort_t* gw3b   = (ushort_t*)(ws + o); o += 131072;    // cvt segment (dead)
  ushort_t* gbb    = (ushort_t*)(ws + o); o += 512;       // 2*128
  ushort_t* sessb  = (ushort_t*)(ws + o); o += 32768;     // 128*128
  ushort_t* hlb    = (ushort_t*)(ws + o); o += 1638400;   // 6400*128
  uint4*    w1f    = (uint4*)(ws + o);    o += 65536;
  uint4*    w3f    = (uint4*)(ws + o);    o += 131072;
  size_t fixed = o;
  (void)alocb; (void)gw1b; (void)gw3b;

  float* outp = (float*)d_out;

  const size_t TPATH_NEED = fixed + 2*(size_t)12800000       // Tt, Tb
                          + (size_t)128*153600               // out1c
                          + (size_t)128*12800                // o0c
                          + (size_t)3*128*600*4;             // score
  bool tpath = (ws_size >= TPATH_NEED);

  // ---- K1: local + sess + cvt + prep ----
  k1<<<K1_GRID_, 256, 0, stream>>>(
      inputs, adj, item, mask_item,
      d_in[6], d_in[7], d_in[8], d_in[9], d_in[10], d_in[11],
      emb_b, w1f, w3f, sessb, hlb, tpath ? 1 : 0);

  if (tpath){
    ushort_t* Tt    = (ushort_t*)(ws + o);  o += 12800000;
    ushort_t* Tb    = (ushort_t*)(ws + o);  o += 12800000;
    ushort_t* out1c = (ushort_t*)(ws + o);  o += (size_t)128*153600;
    ushort_t* o0c   = (ushort_t*)(ws + o);  o += (size_t)128*12800;
    float*    score = (float*)(ws + o);
    int nA600 = 128*600, nA50 = 128*50, nTot = 128*650;

    // K2: score2_ab (nid-prefetch + SW-pipeline) + tprep (4x row reuse)
    k2<<<K2_GRID_, 256, 0, stream>>>(d_in[6], emb_b, w3f, Tt, Tb,
                                     sessb, first_adj, adj_all,
                                     w1f, gw2b, score);
    // K3: gather hop-0 outputs
    gather_out<<<(nTot*64 + 255)/256, 256, 0, stream>>>(inputs, first_adj, adj_all, score,
                                                        Tt, Tb, gbb, o0c, out1c,
                                                        nA50, nTot, nA600);
    // K4: hop-1 scores (SW-pipelined)
    score2_c<<<512, 256, 0, stream>>>(sessb, out1c, w1f + 2048, gw2b + 128, score);
    // K5: hop-1 out + hl add
    out_mfma_c2<<<(nA50 + 63)/64, 256, 0, stream>>>(score, out1c, o0c,
                                                    w3f + 4096, gbb + 128,
                                                    hlb, outp, nA50);
  } else {
    // ---- fallback: round-0 direct chunked path ----
    int CHB = 16;
    if      (ws_size >= fixed + (size_t)128*173600) CHB = 128;
    else if (ws_size >= fixed + (size_t)64 *173600) CHB = 64;
    else if (ws_size >= fixed + (size_t)32 *173600) CHB = 32;
    ushort_t* out1c = (ushort_t*)(ws + o);  o += (size_t)CHB*153600;
    ushort_t* o0c   = (ushort_t*)(ws + o);  o += (size_t)CHB*12800;
    float*    score = (float*)(ws + o);

    int nchunk = B_ / CHB;
    for (int c = 0; c < nchunk; c++){
      int b0 = c * CHB;
      const int* fadj  = first_adj + (size_t)b0 * 600;
      const ushort_t* sbc = sessb + (size_t)b0 * D_;
      ushort_t*  hlc   = hlb  + (size_t)b0 * 50 * D_;
      float*     outc  = outp + (size_t)b0 * 50 * D_;
      int nA600 = CHB*600, nA50 = CHB*50, nTot = CHB*650;

      score_mfma_ab<<<(3*nA600)/128, 256, 0, stream>>>(sbc, emb_b, fadj, adj_all,
                                                       w1f, gw2b, score, nA600);
      out_mfma_ab<<<(nTot + 127)/128, 512, 0, stream>>>(score, inputs + b0*50, fadj, adj_all,
                                                        emb_b, w3f, gbb, o0c, out1c,
                                                        nA50, nTot, nA600);
      score_mfma_c<<<nA600/128, 256, 0, stream>>>(sbc, out1c, w1f + 2048, gw2b + 128, score);
      out_mfma_c<<<(nA50 + 127)/128, 512, 0, stream>>>(score, out1c, o0c,
                                                       w3f + 4096, gbb + 128,
                                                       hlc, outc, nA50);
    }
  }
}